// Round 13
// baseline (407.613 us; speedup 1.0000x reference)
//
#include <hip/hip_runtime.h>
#include <math.h>

#define T_TOT 10
#define NB    8
#define NPG   1080
#define NN    (NB*NPG)      // 8640 nodes
#define DEG   16

typedef unsigned short ushortT;
using short8 = __attribute__((ext_vector_type(8))) short;
using f32x4  = __attribute__((ext_vector_type(4))) float;

__device__ __forceinline__ float lrelu(float v) { return v > 0.f ? v : 0.2f*v; }
__device__ __forceinline__ float elu1(float v)  { return v > 0.f ? v : (__expf(v) - 1.f); }
__device__ __forceinline__ float bf2f(ushortT h){ return __uint_as_float(((unsigned)h) << 16); }
__device__ __forceinline__ float bfl(unsigned u){ return __uint_as_float(u << 16); }
__device__ __forceinline__ float bfh(unsigned u){ return __uint_as_float(u & 0xFFFF0000u); }
__device__ __forceinline__ ushortT rne(float v) {
    unsigned u = __float_as_uint(v);
    u += 0x7FFFu + ((u >> 16) & 1u);
    return (ushortT)(u >> 16);
}
__device__ __forceinline__ unsigned pk2(float a, float b) {
    return (unsigned)rne(a) | ((unsigned)rne(b) << 16);
}
// bijective XCD swizzle (8 XCDs): contiguous work range per XCD (L2 locality).
__device__ __forceinline__ int xswz(int b, int nwg) {
    int q = nwg >> 3, r = nwg & 7;
    int x = b & 7, i = b >> 3;
    return x*q + min(x, r) + i;
}
// async global->LDS 16B: wave-uniform LDS base + lane*16 (HW semantics).
__device__ __forceinline__ void gld16(const void* g, void* lbase, int laneoff) {
#if __has_builtin(__builtin_amdgcn_global_load_lds)
    typedef __attribute__((address_space(1))) const unsigned int GU;
    typedef __attribute__((address_space(3))) unsigned int LU;
    __builtin_amdgcn_global_load_lds((GU*)g, (LU*)lbase, 16, 0, 0);
    (void)laneoff;
#else
    *(uint4*)((char*)lbase + laneoff) = *(const uint4*)g;
#endif
}

// ---------------------------------------------------------------------------
// L1 precompute: A[sd][k][h] = dot(W1[k, h*64:(h+1)*64], att_{s,d}[h,:])
__global__ void k_prep_l1(const float* __restrict__ W1, const float* __restrict__ as1,
                          const float* __restrict__ ad1, float* __restrict__ A) {
    int tid = threadIdx.x;
    if (tid >= 32) return;
    int h = tid & 7, k = (tid >> 3) & 1, sd = tid >> 4;
    const float* att = sd ? ad1 : as1;
    float acc = 0.f;
    for (int c = 0; c < 64; ++c) acc += W1[k*512 + h*64 + c] * att[h*64 + c];
    A[sd*16 + k*8 + h] = acc;
}

// W [K,M] fp32 -> WT [M,K] bf16 (RNE)
__global__ void k_prepW(const float* __restrict__ W, ushortT* __restrict__ WT, int K, int M) {
    int i = blockIdx.x*256 + threadIdx.x;
    if (i >= K*M) return;
    int k = i / M, m = i - k*M;
    WT[(size_t)m*K + k] = rne(W[i]);
}

// Layer-1: fused e-compute (rank-2) + attention + aggregate + linear + ELU -> bf16.
__global__ __launch_bounds__(256) void k_gat1(
    const float* __restrict__ x, const int* __restrict__ esrc,
    const float* __restrict__ A, const float* __restrict__ W1,
    const float* __restrict__ b1, ushortT* __restrict__ q, int R) {
    int tid = threadIdx.x;
    int g = xswz(blockIdx.x, gridDim.x)*32 + (tid >> 3);   // group = r*8 + hh
    int l = tid & 7;
    if (g >= R*8) g = R*8 - 1;
    int r = g >> 3, hh = g & 7;
    int t = r / NN, n = r - t*NN;
    float2 xr = *(const float2*)&x[2*r];
    float As0 = A[hh], As1 = A[8+hh];
    float edv = xr.x*A[16+hh] + xr.y*A[24+hh];
    float ev[3], xs0[3], xs1[3];
    float m = -1e30f;
    #pragma unroll
    for (int s = 0; s < 3; ++s) {
        int j = s*8 + l;
        if (j < 17) {
            int src = (j == 16) ? r : (t*NN + esrc[n*DEG + j]);
            float2 xs = *(const float2*)&x[2*src];
            xs0[s] = xs.x; xs1[s] = xs.y;
            float e = lrelu(xs.x*As0 + xs.y*As1 + edv);
            ev[s] = e; m = fmaxf(m, e);
        } else { ev[s] = -1e30f; xs0[s] = 0.f; xs1[s] = 0.f; }
    }
    #pragma unroll
    for (int off = 4; off >= 1; off >>= 1) m = fmaxf(m, __shfl_xor(m, off, 8));
    float den = 0.f, p0 = 0.f, p1 = 0.f;
    #pragma unroll
    for (int s = 0; s < 3; ++s) {
        float e2 = __expf(ev[s] - m);
        den += e2; p0 += e2*xs0[s]; p1 += e2*xs1[s];
    }
    #pragma unroll
    for (int off = 4; off >= 1; off >>= 1) {
        den += __shfl_xor(den, off, 8);
        p0  += __shfl_xor(p0,  off, 8);
        p1  += __shfl_xor(p1,  off, 8);
    }
    float inv = 1.f/(den + 1e-16f);
    float xa0 = p0*inv, xa1 = p1*inv;
    int col = hh*64 + l*8;
    float4 w0a = *(const float4*)&W1[col],       w0b = *(const float4*)&W1[col+4];
    float4 w1a = *(const float4*)&W1[512+col],   w1b = *(const float4*)&W1[512+col+4];
    float4 bba = *(const float4*)&b1[col],       bbb = *(const float4*)&b1[col+4];
    float v0 = elu1(xa0*w0a.x + xa1*w1a.x + bba.x);
    float v1 = elu1(xa0*w0a.y + xa1*w1a.y + bba.y);
    float v2 = elu1(xa0*w0a.z + xa1*w1a.z + bba.z);
    float v3 = elu1(xa0*w0a.w + xa1*w1a.w + bba.w);
    float v4 = elu1(xa0*w0b.x + xa1*w1b.x + bbb.x);
    float v5 = elu1(xa0*w0b.y + xa1*w1b.y + bbb.y);
    float v6 = elu1(xa0*w0b.z + xa1*w1b.z + bbb.z);
    float v7 = elu1(xa0*w0b.w + xa1*w1b.w + bbb.w);
    uint4 o;
    o.x = pk2(v0,v1); o.y = pk2(v2,v3); o.z = pk2(v4,v5); o.w = pk2(v6,v7);
    *(uint4*)&q[(size_t)r*512 + col] = o;
}

// Generic GAT attention+aggregate (+bias+ELU). Register softmax + shfl
// broadcast; no LDS, no barrier.
template<int H, int C, int LANES, bool BFIN, bool BFOUT>
__global__ __launch_bounds__(256) void k_gat(
    const void* __restrict__ hb_, const int* __restrict__ esrc,
    const float* __restrict__ es, const float* __restrict__ ed,
    const float* __restrict__ bias, float* __restrict__ out,
    ushortT* __restrict__ ohi, int R) {
    constexpr int CPL = C/LANES;                 // 8 (bf16) or 4 (fp32)
    constexpr int GPB = 256/LANES;
    constexpr int EPL = (17 + LANES - 1)/LANES;
    constexpr int HC = H*C;
    int tid = threadIdx.x;
    int l = tid & (LANES-1);
    int g = xswz(blockIdx.x, gridDim.x)*GPB + tid/LANES;   // group = r*H + hh
    if (g >= R*H) g = R*H - 1;
    int r = g / H, hh = g % H;
    int t = r / NN, n = r - t*NN;
    float edv = ed[(size_t)r*H + hh];
    float ev[EPL]; int sv[EPL];
    float m = -1e30f;
    #pragma unroll
    for (int s = 0; s < EPL; ++s) {
        int j = s*LANES + l;
        if (j < 17) {
            int src = (j == 16) ? r : (t*NN + esrc[n*DEG + j]);
            sv[s] = src;
            float e = lrelu(es[(size_t)src*H + hh] + edv);
            ev[s] = e; m = fmaxf(m, e);
        } else { ev[s] = -1e30f; sv[s] = r; }
    }
    #pragma unroll
    for (int off = LANES/2; off >= 1; off >>= 1) m = fmaxf(m, __shfl_xor(m, off, LANES));
    float den = 0.f;
    float wv[EPL];
    #pragma unroll
    for (int s = 0; s < EPL; ++s) {
        float e2 = __expf(ev[s] - m);
        wv[s] = e2; den += e2;
    }
    #pragma unroll
    for (int off = LANES/2; off >= 1; off >>= 1) den += __shfl_xor(den, off, LANES);
    float inv = 1.f/(den + 1e-16f);
    #pragma unroll
    for (int s = 0; s < EPL; ++s) wv[s] *= inv;

    int lb = (tid & 63) & ~(LANES-1);            // group's base lane (abs)
    float acc[CPL] = {};
    #pragma unroll
    for (int j = 0; j < 17; ++j) {
        float wj = __shfl(wv[j/LANES], lb + (j & (LANES-1)), 64);
        int   sj = __shfl(sv[j/LANES], lb + (j & (LANES-1)), 64);
        if constexpr (BFIN) {
            const ushortT* hp = (const ushortT*)hb_ + (size_t)sj*HC + hh*C + l*CPL;
            uint4 hv = *(const uint4*)hp;
            acc[0] += wj*bfl(hv.x); acc[1] += wj*bfh(hv.x);
            acc[2] += wj*bfl(hv.y); acc[3] += wj*bfh(hv.y);
            acc[4] += wj*bfl(hv.z); acc[5] += wj*bfh(hv.z);
            acc[6] += wj*bfl(hv.w); acc[7] += wj*bfh(hv.w);
        } else {
            const float* hp = (const float*)hb_ + (size_t)sj*HC + hh*C + l*CPL;
            float4 hv = *(const float4*)hp;
            acc[0] += wj*hv.x; acc[1] += wj*hv.y;
            acc[2] += wj*hv.z; acc[3] += wj*hv.w;
        }
    }
    int base = hh*C + l*CPL;
    #pragma unroll
    for (int c = 0; c < CPL; ++c) acc[c] = elu1(acc[c] + bias[base + c]);
    if constexpr (BFOUT) {
        uint4 o;
        o.x = pk2(acc[0],acc[1]); o.y = pk2(acc[2],acc[3]);
        o.z = pk2(acc[4],acc[5]); o.w = pk2(acc[6],acc[7]);
        *(uint4*)&ohi[(size_t)r*HC + base] = o;
    } else {
        *(float4*)&out[(size_t)r*HC + base] = make_float4(acc[0],acc[1],acc[2],acc[3]);
    }
}

// MFMA GEMM: Hout[R,M](bf16) = X[R,K](bf16) @ WT[M,K](bf16)^T.
// 128x128 tile, 8 waves (2M x 4N, wave tile 64x32, acc = 32 AGPR), BK=64.
// A: double-buffered LDS (32 KB total -> 4 blocks/CU) via async
// global_load_lds with pre-swizzled source; B: tiny L2-resident weight
// matrix read directly from global per fragment (no LDS). 2-phase:
// stage(next A) issued before compute(cur), one barrier per K-step.
template<int C>
__global__ __launch_bounds__(512) void k_gemm_mfma(
    const ushortT* __restrict__ X, const ushortT* __restrict__ WT,
    const float* __restrict__ as_, const float* __restrict__ ad_,
    ushortT* __restrict__ Hout, float* __restrict__ es, float* __restrict__ ed,
    int R, int K, int M) {
    __shared__ __align__(16) char smem[32768];   // 2 x (A 16K)
    int tid = threadIdx.x;
    int wid = tid >> 6, l = tid & 63;
    int l15 = l & 15, lg = l >> 4;
    int wr = wid >> 2, wc = wid & 3;             // 2M x 4N
    int rb = blockIdx.x*128, cb = blockIdx.y*128;
    const size_t strideB = (size_t)K*2;
    const int nKT = K >> 6;

    f32x4 acc[4][2] = {};
    int aoff[4], asw[4];
    #pragma unroll
    for (int i = 0; i < 4; ++i) {
        int ar = wr*64 + i*16 + l15;
        aoff[i] = ar*128; asw[i] = (ar & 7) << 4;
    }
    // B fragment base pointers (per-lane rows of WT; L2-resident)
    const char* Bp[2];
    #pragma unroll
    for (int j = 0; j < 2; ++j)
        Bp[j] = (const char*)WT + (size_t)(cb + wc*32 + j*16 + l15)*strideB;
    int kb0 = lg*16;
    // staging: row = i*64 + (tid>>3); col invariant (row&7 == (tid>>3)&7)
    int srow = tid >> 3;
    int colb = ((tid & 7)*16) ^ ((srow & 7) << 4);   // pre-swizzled source col

    auto stage = [&](int buf, int kt) {
        int kbyte = kt*128;
        char* base = smem + (buf << 14);
        #pragma unroll
        for (int i = 0; i < 2; ++i) {
            int row = i*64 + srow;
            const char* sa = (const char*)X + (size_t)min(rb + row, R - 1)*strideB + kbyte + colb;
            int dst = (i*64 + wid*8)*128;             // linear LDS dest (wave-uniform)
            gld16(sa, base + dst, l*16);
        }
    };

    stage(0, 0);
    __syncthreads();                             // implicit vmcnt(0) drain
    for (int kt = 0; kt < nKT; ++kt) {
        int cur = kt & 1;
        if (kt + 1 < nKT) stage(cur ^ 1, kt + 1);
        const char* bufp = smem + (cur << 14);
        int kbyte = kt*128;
        #pragma unroll
        for (int ks = 0; ks < 2; ++ks) {
            int kb = ks*64 + kb0;
            short8 ah[4], bv[2];
            #pragma unroll
            for (int j = 0; j < 2; ++j)
                bv[j] = *(const short8*)(Bp[j] + kbyte + kb);
            #pragma unroll
            for (int i = 0; i < 4; ++i)
                ah[i] = *(const short8*)(bufp + aoff[i] + (kb ^ asw[i]));
            #pragma unroll
            for (int mt = 0; mt < 4; ++mt)
                #pragma unroll
                for (int nt = 0; nt < 2; ++nt)
                    acc[mt][nt] = __builtin_amdgcn_mfma_f32_16x16x32_bf16(ah[mt], bv[nt], acc[mt][nt], 0, 0, 0);
        }
        __syncthreads();                         // drains next-tile staging too
    }
    // epilogue: es/ed per head + bf16 store
    constexpr int NSL = 128/C;                   // head slots per block
    constexpr int NHW = 32/C;                    // head slots per wave (32 cols)
    int hg0 = cb / C;
    float asv[2], adv[2];
    #pragma unroll
    for (int nt = 0; nt < 2; ++nt) {
        int col = wc*32 + nt*16 + l15;
        int h = col / C, c = col - h*C;
        asv[nt] = as_[(hg0 + h)*C + c];
        adv[nt] = ad_[(hg0 + h)*C + c];
    }
    float* ebp = (float*)smem;                   // [128][NSL][2]
    #pragma unroll
    for (int mt = 0; mt < 4; ++mt) {
        float ps[4][NHW] = {}, pd[4][NHW] = {};
        #pragma unroll
        for (int nt = 0; nt < 2; ++nt) {
            int sl = (nt*16)/C;
            #pragma unroll
            for (int q = 0; q < 4; ++q) {
                ps[q][sl] += acc[mt][nt][q]*asv[nt];
                pd[q][sl] += acc[mt][nt][q]*adv[nt];
            }
        }
        #pragma unroll
        for (int off = 1; off < 16; off <<= 1)
            #pragma unroll
            for (int q = 0; q < 4; ++q)
                #pragma unroll
                for (int sl = 0; sl < NHW; ++sl) {
                    ps[q][sl] += __shfl_xor(ps[q][sl], off);
                    pd[q][sl] += __shfl_xor(pd[q][sl], off);
                }
        if (l15 == 0) {
            #pragma unroll
            for (int q = 0; q < 4; ++q) {
                int row = wr*64 + mt*16 + lg*4 + q;
                #pragma unroll
                for (int sl = 0; sl < NHW; ++sl) {
                    ebp[(row*NSL + wc*NHW + sl)*2 + 0] = ps[q][sl];
                    ebp[(row*NSL + wc*NHW + sl)*2 + 1] = pd[q][sl];
                }
            }
        }
        #pragma unroll
        for (int nt = 0; nt < 2; ++nt) {
            int col = cb + wc*32 + nt*16 + l15;
            #pragma unroll
            for (int q = 0; q < 4; ++q) {
                int r = rb + wr*64 + mt*16 + lg*4 + q;
                if (r < R) Hout[(size_t)r*M + col] = rne(acc[mt][nt][q]);
            }
        }
    }
    __syncthreads();
    for (int i = tid; i < 128*NSL; i += 512) {
        int row = i / NSL, sl = i - row*NSL;
        int r = rb + row;
        if (r < R) {
            es[(size_t)r*8 + hg0 + sl] = ebp[i*2 + 0];
            ed[(size_t)r*8 + hg0 + sl] = ebp[i*2 + 1];
        }
    }
}

// Layer-4 linear: X[R,128](bf16) @ W4[128,8] + es/ed. 8 lanes/row, lane-split K.
__global__ __launch_bounds__(256) void k_lin4(
    const ushortT* __restrict__ X, const float* __restrict__ W,
    const float* __restrict__ as_, const float* __restrict__ ad_,
    float* __restrict__ Hout, float* __restrict__ es, float* __restrict__ ed, int R) {
    int tid = threadIdx.x;
    int l = tid & 7;
    int r = blockIdx.x*32 + (tid >> 3);
    if (r >= R) return;
    const ushortT* xp = X + (size_t)r*128 + l*16;
    uint4 a = *(const uint4*)xp;
    uint4 b = *(const uint4*)(xp + 8);
    float xv[16];
    xv[0]=bfl(a.x); xv[1]=bfh(a.x); xv[2]=bfl(a.y); xv[3]=bfh(a.y);
    xv[4]=bfl(a.z); xv[5]=bfh(a.z); xv[6]=bfl(a.w); xv[7]=bfh(a.w);
    xv[8]=bfl(b.x); xv[9]=bfh(b.x); xv[10]=bfl(b.y); xv[11]=bfh(b.y);
    xv[12]=bfl(b.z); xv[13]=bfh(b.z); xv[14]=bfl(b.w); xv[15]=bfh(b.w);
    float acc[8] = {};
    #pragma unroll
    for (int kk = 0; kk < 16; ++kk) {
        const float* wr = W + (l*16 + kk)*8;
        float4 wa = *(const float4*)wr, wb = *(const float4*)(wr + 4);
        acc[0] += xv[kk]*wa.x; acc[1] += xv[kk]*wa.y;
        acc[2] += xv[kk]*wa.z; acc[3] += xv[kk]*wa.w;
        acc[4] += xv[kk]*wb.x; acc[5] += xv[kk]*wb.y;
        acc[6] += xv[kk]*wb.z; acc[7] += xv[kk]*wb.w;
    }
    #pragma unroll
    for (int off = 4; off >= 1; off >>= 1)
        #pragma unroll
        for (int c = 0; c < 8; ++c) acc[c] += __shfl_xor(acc[c], off, 8);
    if (l == 0) {
        *(float4*)&Hout[(size_t)r*8]     = make_float4(acc[0],acc[1],acc[2],acc[3]);
        *(float4*)&Hout[(size_t)r*8 + 4] = make_float4(acc[4],acc[5],acc[6],acc[7]);
        float ps = 0.f, pd = 0.f;
        #pragma unroll
        for (int c = 0; c < 8; ++c) { ps += acc[c]*as_[c]; pd += acc[c]*ad_[c]; }
        es[r] = ps; ed[r] = pd;
    }
}

// Mean-pool per (t, graph): out4[R,8] -> emb[T,B,8]
__global__ void k_pool(const float* __restrict__ x4, float* __restrict__ emb, int t0) {
    __shared__ float red[256];
    int tl = blockIdx.x >> 3, b = blockIdx.x & 7;
    int tid = threadIdx.x;
    int c = tid & 7, nl = tid >> 3;
    float s = 0.f;
    for (int k = 0; k < 34; ++k) {
        int n = nl + 32*k;
        if (n < NPG) s += x4[((size_t)tl*NN + b*NPG + n)*8 + c];
    }
    red[tid] = s;
    __syncthreads();
    for (int st = 16; st >= 1; st >>= 1) {
        if (nl < st) red[tid] += red[tid + st*8];
        __syncthreads();
    }
    if (nl == 0) emb[((t0 + tl)*8 + b)*8 + c] = red[c] * (1.f/1080.f);
}

// LSTM (one block per batch element) + final FC. Register-resident w_hh row.
__global__ __launch_bounds__(512) void k_lstm(
    const float* __restrict__ emb, const float* __restrict__ w_ih,
    const float* __restrict__ w_hh, const float* __restrict__ b_ih,
    const float* __restrict__ b_hh, const float* __restrict__ w_fc,
    const float* __restrict__ b_fc, float* __restrict__ out) {
    int b = blockIdx.x, u = threadIdx.x;
    __shared__ float h[128], cst[128], g[512], eall[T_TOT*8];
    if (u < 128) { h[u] = 0.f; cst[u] = 0.f; }
    if (u < T_TOT*8) eall[u] = emb[((u >> 3)*8 + b)*8 + (u & 7)];
    float wreg[128];
    {
        const float* wp = w_hh + (size_t)u*128;
        #pragma unroll
        for (int k4 = 0; k4 < 32; ++k4) {
            float4 v = *(const float4*)&wp[k4*4];
            wreg[4*k4+0] = v.x; wreg[4*k4+1] = v.y;
            wreg[4*k4+2] = v.z; wreg[4*k4+3] = v.w;
        }
    }
    float wih[8];
    #pragma unroll
    for (int k = 0; k < 8; ++k) wih[k] = w_ih[(size_t)u*8 + k];
    float bsum = b_ih[u] + b_hh[u];
    __syncthreads();
    for (int t = 0; t < T_TOT; ++t) {
        float a0 = bsum, a1 = 0.f, a2 = 0.f, a3 = 0.f;
        #pragma unroll
        for (int k = 0; k < 8; ++k) a0 += eall[t*8 + k]*wih[k];
        #pragma unroll
        for (int k = 0; k < 32; ++k) {
            a0 += h[4*k+0]*wreg[4*k+0];
            a1 += h[4*k+1]*wreg[4*k+1];
            a2 += h[4*k+2]*wreg[4*k+2];
            a3 += h[4*k+3]*wreg[4*k+3];
        }
        g[u] = (a0 + a1) + (a2 + a3);
        __syncthreads();
        if (u < 128) {
            float ig = 1.f/(1.f + __expf(-g[u]));
            float fg = 1.f/(1.f + __expf(-g[128+u]));
            float gg = tanhf(g[256+u]);
            float og = 1.f/(1.f + __expf(-g[384+u]));
            float cn = fg*cst[u] + ig*gg;
            cst[u] = cn;
            h[u] = og*tanhf(cn);
        }
        __syncthreads();
    }
    if (u < 64) {
        float p0 = h[u]*w_fc[u]       + h[u+64]*w_fc[64+u];
        float p1 = h[u]*w_fc[128+u]   + h[u+64]*w_fc[192+u];
        #pragma unroll
        for (int off = 32; off >= 1; off >>= 1) {
            p0 += __shfl_xor(p0, off, 64);
            p1 += __shfl_xor(p1, off, 64);
        }
        if (u == 0) {
            out[b*2 + 0] = p0 + b_fc[0];
            out[b*2 + 1] = p1 + b_fc[1];
        }
    }
}

extern "C" void kernel_launch(void* const* d_in, const int* in_sizes, int n_in,
                              void* d_out, int out_size, void* d_ws, size_t ws_size,
                              hipStream_t stream) {
    const float* x_seq = (const float*)d_in[0];
    const int*   edge  = (const int*)d_in[1];   // row0 = src
    const float* W1 = (const float*)d_in[3];
    const float* as1 = (const float*)d_in[4];
    const float* ad1 = (const float*)d_in[5];
    const float* b1  = (const float*)d_in[6];
    const float* W2 = (const float*)d_in[7];
    const float* as2 = (const float*)d_in[8];
    const float* ad2 = (const float*)d_in[9];
    const float* b2  = (const float*)d_in[10];
    const float* W3 = (const float*)d_in[11];
    const float* as3 = (const float*)d_in[12];
    const float* ad3 = (const float*)d_in[13];
    const float* b3  = (const float*)d_in[14];
    const float* W4 = (const float*)d_in[15];
    const float* as4 = (const float*)d_in[16];
    const float* ad4 = (const float*)d_in[17];
    const float* b4  = (const float*)d_in[18];
    const float* w_ih = (const float*)d_in[19];
    const float* w_hh = (const float*)d_in[20];
    const float* b_ih = (const float*)d_in[21];
    const float* b_hh = (const float*)d_in[22];
    const float* w_fc = (const float*)d_in[23];
    const float* b_fc = (const float*)d_in[24];

    char* w = (char*)d_ws;
    auto alloc = [&](size_t bytes) {
        char* p = w; w += (bytes + 255) & ~(size_t)255; return p;
    };
    float*   A1  = (float*)alloc(128);
    float*   emb = (float*)alloc((size_t)T_TOT*8*8*4);
    ushortT* W2T = (ushortT*)alloc((size_t)256*512*2);
    ushortT* W3T = (ushortT*)alloc((size_t)128*256*2);
    size_t used = (size_t)(w - (char*)d_ws);
    // per-row bytes: Q 1024 + P 512 + G3 512 + H3 256 + G4 256 + 4 vecs x32
    size_t perT = (size_t)NN*(1024 + 512 + 512 + 256 + 256 + 128);
    size_t rem = (ws_size > used + 4096) ? ws_size - used - 4096 : 0;
    int Tc = (int)(rem / perT);
    if (Tc > T_TOT) Tc = T_TOT;
    if (Tc < 1) Tc = 1;
    ushortT* Q  = (ushortT*)alloc((size_t)Tc*NN*1024);
    ushortT* P  = (ushortT*)alloc((size_t)Tc*NN*512);
    ushortT* G3 = (ushortT*)alloc((size_t)Tc*NN*512);
    ushortT* H3 = (ushortT*)alloc((size_t)Tc*NN*256);
    ushortT* G4 = (ushortT*)alloc((size_t)Tc*NN*256);
    float*   ES = (float*)alloc((size_t)Tc*NN*32);
    float*   ED = (float*)alloc((size_t)Tc*NN*32);
    float*   P4 = (float*)alloc((size_t)Tc*NN*32);
    float*   G5 = (float*)alloc((size_t)Tc*NN*32);

    k_prep_l1<<<1, 64, 0, stream>>>(W1, as1, ad1, A1);
    k_prepW<<<(256*512 + 255)/256, 256, 0, stream>>>(W2, W2T, 512, 256);
    k_prepW<<<(128*256 + 255)/256, 256, 0, stream>>>(W3, W3T, 256, 128);

    for (int t0 = 0; t0 < T_TOT; t0 += Tc) {
        int tc = (Tc < T_TOT - t0) ? Tc : (T_TOT - t0);
        int R = tc*NN;
        int nrb = (R + 127)/128;
        const float* xoff = x_seq + (size_t)t0*NN*2;
        // Layer 1 (rank-2 + fused e-compute) -> bf16
        k_gat1<<<(R*8 + 31)/32, 256, 0, stream>>>(xoff, edge, A1, W1, b1, Q, R);
        // Layer 2: MFMA GEMM 512->256 (+es/ed), agg -> bf16
        k_gemm_mfma<32><<<dim3(nrb, 2), 512, 0, stream>>>(Q, W2T, as2, ad2, P, ES, ED, R, 512, 256);
        k_gat<8,32,4,true,true><<<(R*8 + 63)/64, 256, 0, stream>>>(P, edge, ES, ED, b2, nullptr, G3, R);
        // Layer 3: MFMA GEMM 256->128 (+es/ed), agg -> bf16
        k_gemm_mfma<16><<<dim3(nrb, 1), 512, 0, stream>>>(G3, W3T, as3, ad3, H3, ES, ED, R, 256, 128);
        k_gat<8,16,2,true,true><<<(R*8 + 127)/128, 256, 0, stream>>>(H3, edge, ES, ED, b3, nullptr, G4, R);
        // Layer 4: linear 128->8 (+es/ed), agg (fp32)
        k_lin4<<<(R + 31)/32, 256, 0, stream>>>(G4, W4, as4, ad4, P4, ES, ED, R);
        k_gat<1,8,2,false,false><<<(R + 127)/128, 256, 0, stream>>>(P4, edge, ES, ED, b4, G5, nullptr, R);
        // Pool
        k_pool<<<tc*8, 256, 0, stream>>>(G5, emb, t0);
    }
    k_lstm<<<8, 512, 0, stream>>>(emb, w_ih, w_hh, b_ih, b_hh, w_fc, b_fc, (float*)d_out);
}

// Round 14
// 379.243 us; speedup vs baseline: 1.0748x; 1.0748x over previous
//
#include <hip/hip_runtime.h>
#include <math.h>

#define T_TOT 10
#define NB    8
#define NPG   1080
#define NN    (NB*NPG)      // 8640 nodes
#define DEG   16

typedef unsigned short ushortT;
using short8 = __attribute__((ext_vector_type(8))) short;
using f32x4  = __attribute__((ext_vector_type(4))) float;

__device__ __forceinline__ float lrelu(float v) { return v > 0.f ? v : 0.2f*v; }
__device__ __forceinline__ float elu1(float v)  { return v > 0.f ? v : (__expf(v) - 1.f); }
__device__ __forceinline__ float bfl(unsigned u){ return __uint_as_float(u << 16); }
__device__ __forceinline__ float bfh(unsigned u){ return __uint_as_float(u & 0xFFFF0000u); }
__device__ __forceinline__ ushortT rne(float v) {
    unsigned u = __float_as_uint(v);
    u += 0x7FFFu + ((u >> 16) & 1u);
    return (ushortT)(u >> 16);
}
__device__ __forceinline__ unsigned pk2(float a, float b) {
    return (unsigned)rne(a) | ((unsigned)rne(b) << 16);
}
// bijective XCD swizzle (8 XCDs): contiguous work range per XCD (L2 locality).
__device__ __forceinline__ int xswz(int b, int nwg) {
    int q = nwg >> 3, r = nwg & 7;
    int x = b & 7, i = b >> 3;
    return x*q + min(x, r) + i;
}
// async global->LDS 16B: wave-uniform LDS base + lane*16 (HW semantics).
__device__ __forceinline__ void gld16(const void* g, void* lbase, int laneoff) {
#if __has_builtin(__builtin_amdgcn_global_load_lds)
    typedef __attribute__((address_space(1))) const unsigned int GU;
    typedef __attribute__((address_space(3))) unsigned int LU;
    __builtin_amdgcn_global_load_lds((GU*)g, (LU*)lbase, 16, 0, 0);
    (void)laneoff;
#else
    *(uint4*)((char*)lbase + laneoff) = *(const uint4*)g;
#endif
}

// ---------------------------------------------------------------------------
// L1 precompute: A[sd][k][h] = dot(W1[k, h*64:(h+1)*64], att_{s,d}[h,:])
__global__ void k_prep_l1(const float* __restrict__ W1, const float* __restrict__ as1,
                          const float* __restrict__ ad1, float* __restrict__ A) {
    int tid = threadIdx.x;
    if (tid >= 32) return;
    int h = tid & 7, k = (tid >> 3) & 1, sd = tid >> 4;
    const float* att = sd ? ad1 : as1;
    float acc = 0.f;
    for (int c = 0; c < 64; ++c) acc += W1[k*512 + h*64 + c] * att[h*64 + c];
    A[sd*16 + k*8 + h] = acc;
}

// W [K,M] fp32 -> WT [M,K] bf16 (RNE)
__global__ void k_prepW(const float* __restrict__ W, ushortT* __restrict__ WT, int K, int M) {
    int i = blockIdx.x*256 + threadIdx.x;
    if (i >= K*M) return;
    int k = i / M, m = i - k*M;
    WT[(size_t)m*K + k] = rne(W[i]);
}

// Layer-1: fused e-compute (rank-2) + attention + aggregate + linear + ELU -> bf16.
__global__ __launch_bounds__(256) void k_gat1(
    const float* __restrict__ x, const int* __restrict__ esrc,
    const float* __restrict__ A, const float* __restrict__ W1,
    const float* __restrict__ b1, ushortT* __restrict__ q, int R) {
    int tid = threadIdx.x;
    int g = xswz(blockIdx.x, gridDim.x)*32 + (tid >> 3);   // group = r*8 + hh
    int l = tid & 7;
    if (g >= R*8) g = R*8 - 1;
    int r = g >> 3, hh = g & 7;
    int t = r / NN, n = r - t*NN;
    float2 xr = *(const float2*)&x[2*r];
    float As0 = A[hh], As1 = A[8+hh];
    float edv = xr.x*A[16+hh] + xr.y*A[24+hh];
    float ev[3], xs0[3], xs1[3];
    float m = -1e30f;
    #pragma unroll
    for (int s = 0; s < 3; ++s) {
        int j = s*8 + l;
        if (j < 17) {
            int src = (j == 16) ? r : (t*NN + esrc[n*DEG + j]);
            float2 xs = *(const float2*)&x[2*src];
            xs0[s] = xs.x; xs1[s] = xs.y;
            float e = lrelu(xs.x*As0 + xs.y*As1 + edv);
            ev[s] = e; m = fmaxf(m, e);
        } else { ev[s] = -1e30f; xs0[s] = 0.f; xs1[s] = 0.f; }
    }
    #pragma unroll
    for (int off = 4; off >= 1; off >>= 1) m = fmaxf(m, __shfl_xor(m, off, 8));
    float den = 0.f, p0 = 0.f, p1 = 0.f;
    #pragma unroll
    for (int s = 0; s < 3; ++s) {
        float e2 = __expf(ev[s] - m);
        den += e2; p0 += e2*xs0[s]; p1 += e2*xs1[s];
    }
    #pragma unroll
    for (int off = 4; off >= 1; off >>= 1) {
        den += __shfl_xor(den, off, 8);
        p0  += __shfl_xor(p0,  off, 8);
        p1  += __shfl_xor(p1,  off, 8);
    }
    float inv = 1.f/(den + 1e-16f);
    float xa0 = p0*inv, xa1 = p1*inv;
    int col = hh*64 + l*8;
    float4 w0a = *(const float4*)&W1[col],       w0b = *(const float4*)&W1[col+4];
    float4 w1a = *(const float4*)&W1[512+col],   w1b = *(const float4*)&W1[512+col+4];
    float4 bba = *(const float4*)&b1[col],       bbb = *(const float4*)&b1[col+4];
    float v0 = elu1(xa0*w0a.x + xa1*w1a.x + bba.x);
    float v1 = elu1(xa0*w0a.y + xa1*w1a.y + bba.y);
    float v2 = elu1(xa0*w0a.z + xa1*w1a.z + bba.z);
    float v3 = elu1(xa0*w0a.w + xa1*w1a.w + bba.w);
    float v4 = elu1(xa0*w0b.x + xa1*w1b.x + bbb.x);
    float v5 = elu1(xa0*w0b.y + xa1*w1b.y + bbb.y);
    float v6 = elu1(xa0*w0b.z + xa1*w1b.z + bbb.z);
    float v7 = elu1(xa0*w0b.w + xa1*w1b.w + bbb.w);
    uint4 o;
    o.x = pk2(v0,v1); o.y = pk2(v2,v3); o.z = pk2(v4,v5); o.w = pk2(v6,v7);
    *(uint4*)&q[(size_t)r*512 + col] = o;
}

// Generic GAT attention+aggregate (+bias+ELU). Register softmax + shfl
// broadcast; no LDS, no barrier. (Used for layer 2.)
template<int H, int C, int LANES, bool BFIN, bool BFOUT>
__global__ __launch_bounds__(256) void k_gat(
    const void* __restrict__ hb_, const int* __restrict__ esrc,
    const float* __restrict__ es, const float* __restrict__ ed,
    const float* __restrict__ bias, float* __restrict__ out,
    ushortT* __restrict__ ohi, int R) {
    constexpr int CPL = C/LANES;
    constexpr int GPB = 256/LANES;
    constexpr int EPL = (17 + LANES - 1)/LANES;
    constexpr int HC = H*C;
    int tid = threadIdx.x;
    int l = tid & (LANES-1);
    int g = xswz(blockIdx.x, gridDim.x)*GPB + tid/LANES;   // group = r*H + hh
    if (g >= R*H) g = R*H - 1;
    int r = g / H, hh = g % H;
    int t = r / NN, n = r - t*NN;
    float edv = ed[(size_t)r*H + hh];
    float ev[EPL]; int sv[EPL];
    float m = -1e30f;
    #pragma unroll
    for (int s = 0; s < EPL; ++s) {
        int j = s*LANES + l;
        if (j < 17) {
            int src = (j == 16) ? r : (t*NN + esrc[n*DEG + j]);
            sv[s] = src;
            float e = lrelu(es[(size_t)src*H + hh] + edv);
            ev[s] = e; m = fmaxf(m, e);
        } else { ev[s] = -1e30f; sv[s] = r; }
    }
    #pragma unroll
    for (int off = LANES/2; off >= 1; off >>= 1) m = fmaxf(m, __shfl_xor(m, off, LANES));
    float den = 0.f;
    float wv[EPL];
    #pragma unroll
    for (int s = 0; s < EPL; ++s) {
        float e2 = __expf(ev[s] - m);
        wv[s] = e2; den += e2;
    }
    #pragma unroll
    for (int off = LANES/2; off >= 1; off >>= 1) den += __shfl_xor(den, off, LANES);
    float inv = 1.f/(den + 1e-16f);
    #pragma unroll
    for (int s = 0; s < EPL; ++s) wv[s] *= inv;

    int lb = (tid & 63) & ~(LANES-1);            // group's base lane (abs)
    float acc[CPL] = {};
    #pragma unroll
    for (int j = 0; j < 17; ++j) {
        float wj = __shfl(wv[j/LANES], lb + (j & (LANES-1)), 64);
        int   sj = __shfl(sv[j/LANES], lb + (j & (LANES-1)), 64);
        if constexpr (BFIN) {
            const ushortT* hp = (const ushortT*)hb_ + (size_t)sj*HC + hh*C + l*CPL;
            uint4 hv = *(const uint4*)hp;
            acc[0] += wj*bfl(hv.x); acc[1] += wj*bfh(hv.x);
            acc[2] += wj*bfl(hv.y); acc[3] += wj*bfh(hv.y);
            acc[4] += wj*bfl(hv.z); acc[5] += wj*bfh(hv.z);
            acc[6] += wj*bfl(hv.w); acc[7] += wj*bfh(hv.w);
        } else {
            const float* hp = (const float*)hb_ + (size_t)sj*HC + hh*C + l*CPL;
            float4 hv = *(const float4*)hp;
            acc[0] += wj*hv.x; acc[1] += wj*hv.y;
            acc[2] += wj*hv.z; acc[3] += wj*hv.w;
        }
    }
    int base = hh*C + l*CPL;
    #pragma unroll
    for (int c = 0; c < CPL; ++c) acc[c] = elu1(acc[c] + bias[base + c]);
    if constexpr (BFOUT) {
        uint4 o;
        o.x = pk2(acc[0],acc[1]); o.y = pk2(acc[2],acc[3]);
        o.z = pk2(acc[4],acc[5]); o.w = pk2(acc[6],acc[7]);
        *(uint4*)&ohi[(size_t)r*HC + base] = o;
    } else {
        *(float4*)&out[(size_t)r*HC + base] = make_float4(acc[0],acc[1],acc[2],acc[3]);
    }
}

// Layer-3 aggregate (H=8,C=16 bf16 in) FUSED with layer-4 linear 128->8.
// 2 lanes per (r,hh); row r = 16 consecutive lanes of one wave. G4 never
// materialized: per-lane 8 fp32 channels -> 64 FMA partial + width-16 shfl
// reduce -> H4[r,8] + es4/ed4. Layer-4 e-values go to SEPARATE arrays
// (ES4/ED4) to avoid racing the layer-3 es/ed still being read.
__global__ __launch_bounds__(256) void k_gat3_lin4(
    const ushortT* __restrict__ hb, const int* __restrict__ esrc,
    const float* __restrict__ es, const float* __restrict__ ed,
    const float* __restrict__ bias, const float* __restrict__ W4,
    const float* __restrict__ as4, const float* __restrict__ ad4,
    float* __restrict__ H4, float* __restrict__ es4, float* __restrict__ ed4,
    int R) {
    int tid = threadIdx.x;
    int l = tid & 1;
    int g = xswz(blockIdx.x, gridDim.x)*128 + (tid >> 1);  // group = r*8 + hh
    if (g >= R*8) g = R*8 - 1;
    int r = g >> 3, hh = g & 7;
    int t = r / NN, n = r - t*NN;
    float edv = ed[(size_t)r*8 + hh];
    float ev[9]; int sv[9];
    float m = -1e30f;
    #pragma unroll
    for (int s = 0; s < 9; ++s) {
        int j = s*2 + l;
        if (j < 17) {
            int src = (j == 16) ? r : (t*NN + esrc[n*DEG + j]);
            sv[s] = src;
            float e = lrelu(es[(size_t)src*8 + hh] + edv);
            ev[s] = e; m = fmaxf(m, e);
        } else { ev[s] = -1e30f; sv[s] = r; }
    }
    m = fmaxf(m, __shfl_xor(m, 1, 2));
    float den = 0.f, wv[9];
    #pragma unroll
    for (int s = 0; s < 9; ++s) {
        float e2 = __expf(ev[s] - m);
        wv[s] = e2; den += e2;
    }
    den += __shfl_xor(den, 1, 2);
    float inv = 1.f/(den + 1e-16f);
    #pragma unroll
    for (int s = 0; s < 9; ++s) wv[s] *= inv;

    int lb = (tid & 63) & ~1;
    float acc[8] = {};
    #pragma unroll
    for (int j = 0; j < 17; ++j) {
        float wj = __shfl(wv[j >> 1], lb + (j & 1), 64);
        int   sj = __shfl(sv[j >> 1], lb + (j & 1), 64);
        const ushortT* hp = hb + (size_t)sj*128 + hh*16 + l*8;
        uint4 hv = *(const uint4*)hp;
        acc[0] += wj*bfl(hv.x); acc[1] += wj*bfh(hv.x);
        acc[2] += wj*bfl(hv.y); acc[3] += wj*bfh(hv.y);
        acc[4] += wj*bfl(hv.z); acc[5] += wj*bfh(hv.z);
        acc[6] += wj*bfl(hv.w); acc[7] += wj*bfh(hv.w);
    }
    int c0 = hh*16 + l*8;
    #pragma unroll
    for (int k = 0; k < 8; ++k) acc[k] = elu1(acc[k] + bias[c0 + k]);
    // fused layer-4 linear
    float pj[8] = {};
    #pragma unroll
    for (int k = 0; k < 8; ++k) {
        const float* wr = W4 + (size_t)(c0 + k)*8;
        float4 wa = *(const float4*)wr, wb = *(const float4*)(wr + 4);
        pj[0] += acc[k]*wa.x; pj[1] += acc[k]*wa.y;
        pj[2] += acc[k]*wa.z; pj[3] += acc[k]*wa.w;
        pj[4] += acc[k]*wb.x; pj[5] += acc[k]*wb.y;
        pj[6] += acc[k]*wb.z; pj[7] += acc[k]*wb.w;
    }
    #pragma unroll
    for (int off = 1; off <= 8; off <<= 1)
        #pragma unroll
        for (int j = 0; j < 8; ++j) pj[j] += __shfl_xor(pj[j], off, 16);
    if ((tid & 15) == 0) {
        *(float4*)&H4[(size_t)r*8]     = make_float4(pj[0],pj[1],pj[2],pj[3]);
        *(float4*)&H4[(size_t)r*8 + 4] = make_float4(pj[4],pj[5],pj[6],pj[7]);
        float ps = 0.f, pd = 0.f;
        #pragma unroll
        for (int j = 0; j < 8; ++j) { ps += pj[j]*as4[j]; pd += pj[j]*ad4[j]; }
        es4[r] = ps; ed4[r] = pd;
    }
}

// Layer-4 aggregate (H=1,C=8 fp32 in) FUSED with mean-pool. Block covers 128
// consecutive rows (<=2 graphs): LDS bins + atomicAdd into emb (pre-zeroed).
__global__ __launch_bounds__(256) void k_gat4_pool(
    const float* __restrict__ hb, const int* __restrict__ esrc,
    const float* __restrict__ es, const float* __restrict__ ed,
    const float* __restrict__ bias, float* __restrict__ emb,
    int R, int t0) {
    __shared__ float bins[2][8];
    int tid = threadIdx.x;
    if (tid < 16) bins[tid >> 3][tid & 7] = 0.f;
    __syncthreads();
    int l = tid & 1;
    int rb0 = xswz(blockIdx.x, gridDim.x)*128;
    int g = rb0 + (tid >> 1);
    bool dup = false;
    if (g >= R) { g = R - 1; dup = true; }
    int r = g;
    int t = r / NN, n = r - t*NN;
    float edv = ed[r];
    float ev[9]; int sv[9];
    float m = -1e30f;
    #pragma unroll
    for (int s = 0; s < 9; ++s) {
        int j = s*2 + l;
        if (j < 17) {
            int src = (j == 16) ? r : (t*NN + esrc[n*DEG + j]);
            sv[s] = src;
            float e = lrelu(es[src] + edv);
            ev[s] = e; m = fmaxf(m, e);
        } else { ev[s] = -1e30f; sv[s] = r; }
    }
    m = fmaxf(m, __shfl_xor(m, 1, 2));
    float den = 0.f, wv[9];
    #pragma unroll
    for (int s = 0; s < 9; ++s) {
        float e2 = __expf(ev[s] - m);
        wv[s] = e2; den += e2;
    }
    den += __shfl_xor(den, 1, 2);
    float inv = 1.f/(den + 1e-16f);
    #pragma unroll
    for (int s = 0; s < 9; ++s) wv[s] *= inv;

    int lb = (tid & 63) & ~1;
    float acc[4] = {};
    #pragma unroll
    for (int j = 0; j < 17; ++j) {
        float wj = __shfl(wv[j >> 1], lb + (j & 1), 64);
        int   sj = __shfl(sv[j >> 1], lb + (j & 1), 64);
        float4 hv = *(const float4*)&hb[(size_t)sj*8 + l*4];
        acc[0] += wj*hv.x; acc[1] += wj*hv.y;
        acc[2] += wj*hv.z; acc[3] += wj*hv.w;
    }
    #pragma unroll
    for (int c = 0; c < 4; ++c) acc[c] = elu1(acc[c] + bias[l*4 + c]);
    if (!dup) {
        int bin = r/NPG - rb0/NPG;               // 0 or 1
        #pragma unroll
        for (int c = 0; c < 4; ++c) atomicAdd(&bins[bin][l*4 + c], acc[c]);
    }
    __syncthreads();
    if (tid < 16) {
        int bin = tid >> 3, c = tid & 7;
        int erow = rb0/NPG + bin;
        if (erow < R/NPG)
            atomicAdd(&emb[(t0*8 + erow)*8 + c], bins[bin][c]*(1.f/1080.f));
    }
}

// MFMA GEMM (r11 structure, proven 55us): 128x128 tile, 8 waves (2M x 4N,
// wave tile 64x32, acc = 32 AGPR), BK=64. Double-buffered LDS (64 KB) +
// async global_load_lds (linear dest, pre-swizzled source), 2-phase.
template<int C>
__global__ __launch_bounds__(512) void k_gemm_mfma(
    const ushortT* __restrict__ X, const ushortT* __restrict__ WT,
    const float* __restrict__ as_, const float* __restrict__ ad_,
    ushortT* __restrict__ Hout, float* __restrict__ es, float* __restrict__ ed,
    int R, int K, int M) {
    __shared__ __align__(16) char smem[65536];   // 2 x (A 16K | B 16K)
    int tid = threadIdx.x;
    int wid = tid >> 6, l = tid & 63;
    int l15 = l & 15, lg = l >> 4;
    int wr = wid >> 2, wc = wid & 3;             // 2M x 4N
    int rb = blockIdx.x*128, cb = blockIdx.y*128;
    const size_t strideB = (size_t)K*2;
    const int nKT = K >> 6;

    f32x4 acc[4][2] = {};
    int aoff[4], asw[4], boff[2], bsw[2];
    #pragma unroll
    for (int i = 0; i < 4; ++i) {
        int ar = wr*64 + i*16 + l15;
        aoff[i] = ar*128; asw[i] = (ar & 7) << 4;
    }
    #pragma unroll
    for (int j = 0; j < 2; ++j) {
        int bc = wc*32 + j*16 + l15;
        boff[j] = 16384 + bc*128; bsw[j] = (bc & 7) << 4;
    }
    int kb0 = lg*16;
    int srow = tid >> 3;
    int colb = ((tid & 7)*16) ^ ((srow & 7) << 4);   // pre-swizzled source col

    auto stage = [&](int buf, int kt) {
        int kbyte = kt*128;
        char* base = smem + (buf << 15);
        #pragma unroll
        for (int i = 0; i < 2; ++i) {
            int row = i*64 + srow;
            const char* sa = (const char*)X  + (size_t)min(rb + row, R - 1)*strideB + kbyte + colb;
            const char* sb = (const char*)WT + (size_t)(cb + row)*strideB + kbyte + colb;
            int dst = (i*64 + wid*8)*128;             // linear LDS dest (wave-uniform)
            gld16(sa, base + dst,         l*16);
            gld16(sb, base + 16384 + dst, l*16);
        }
    };

    stage(0, 0);
    __syncthreads();
    for (int kt = 0; kt < nKT; ++kt) {
        int cur = kt & 1;
        if (kt + 1 < nKT) stage(cur ^ 1, kt + 1);
        const char* bufp = smem + (cur << 15);
        #pragma unroll
        for (int ks = 0; ks < 2; ++ks) {
            int kb = ks*64 + kb0;
            short8 ah[4], bv[2];
            #pragma unroll
            for (int i = 0; i < 4; ++i)
                ah[i] = *(const short8*)(bufp + aoff[i] + (kb ^ asw[i]));
            #pragma unroll
            for (int j = 0; j < 2; ++j)
                bv[j] = *(const short8*)(bufp + boff[j] + (kb ^ bsw[j]));
            #pragma unroll
            for (int mt = 0; mt < 4; ++mt)
                #pragma unroll
                for (int nt = 0; nt < 2; ++nt)
                    acc[mt][nt] = __builtin_amdgcn_mfma_f32_16x16x32_bf16(ah[mt], bv[nt], acc[mt][nt], 0, 0, 0);
        }
        __syncthreads();
    }
    // epilogue: es/ed per head + bf16 store
    constexpr int NSL = 128/C;
    constexpr int NHW = 32/C;
    int hg0 = cb / C;
    float asv[2], adv[2];
    #pragma unroll
    for (int nt = 0; nt < 2; ++nt) {
        int col = wc*32 + nt*16 + l15;
        int h = col / C, c = col - h*C;
        asv[nt] = as_[(hg0 + h)*C + c];
        adv[nt] = ad_[(hg0 + h)*C + c];
    }
    float* ebp = (float*)smem;                   // [128][NSL][2]
    #pragma unroll
    for (int mt = 0; mt < 4; ++mt) {
        float ps[4][NHW] = {}, pd[4][NHW] = {};
        #pragma unroll
        for (int nt = 0; nt < 2; ++nt) {
            int sl = (nt*16)/C;
            #pragma unroll
            for (int q = 0; q < 4; ++q) {
                ps[q][sl] += acc[mt][nt][q]*asv[nt];
                pd[q][sl] += acc[mt][nt][q]*adv[nt];
            }
        }
        #pragma unroll
        for (int off = 1; off < 16; off <<= 1)
            #pragma unroll
            for (int q = 0; q < 4; ++q)
                #pragma unroll
                for (int sl = 0; sl < NHW; ++sl) {
                    ps[q][sl] += __shfl_xor(ps[q][sl], off);
                    pd[q][sl] += __shfl_xor(pd[q][sl], off);
                }
        if (l15 == 0) {
            #pragma unroll
            for (int q = 0; q < 4; ++q) {
                int row = wr*64 + mt*16 + lg*4 + q;
                #pragma unroll
                for (int sl = 0; sl < NHW; ++sl) {
                    ebp[(row*NSL + wc*NHW + sl)*2 + 0] = ps[q][sl];
                    ebp[(row*NSL + wc*NHW + sl)*2 + 1] = pd[q][sl];
                }
            }
        }
        #pragma unroll
        for (int nt = 0; nt < 2; ++nt) {
            int col = cb + wc*32 + nt*16 + l15;
            #pragma unroll
            for (int q = 0; q < 4; ++q) {
                int r = rb + wr*64 + mt*16 + lg*4 + q;
                if (r < R) Hout[(size_t)r*M + col] = rne(acc[mt][nt][q]);
            }
        }
    }
    __syncthreads();
    for (int i = tid; i < 128*NSL; i += 512) {
        int row = i / NSL, sl = i - row*NSL;
        int r = rb + row;
        if (r < R) {
            es[(size_t)r*8 + hg0 + sl] = ebp[i*2 + 0];
            ed[(size_t)r*8 + hg0 + sl] = ebp[i*2 + 1];
        }
    }
}

// LSTM (one block per batch element) + final FC. Register-resident w_hh row.
__global__ __launch_bounds__(512) void k_lstm(
    const float* __restrict__ emb, const float* __restrict__ w_ih,
    const float* __restrict__ w_hh, const float* __restrict__ b_ih,
    const float* __restrict__ b_hh, const float* __restrict__ w_fc,
    const float* __restrict__ b_fc, float* __restrict__ out) {
    int b = blockIdx.x, u = threadIdx.x;
    __shared__ float h[128], cst[128], g[512], eall[T_TOT*8];
    if (u < 128) { h[u] = 0.f; cst[u] = 0.f; }
    if (u < T_TOT*8) eall[u] = emb[((u >> 3)*8 + b)*8 + (u & 7)];
    float wreg[128];
    {
        const float* wp = w_hh + (size_t)u*128;
        #pragma unroll
        for (int k4 = 0; k4 < 32; ++k4) {
            float4 v = *(const float4*)&wp[k4*4];
            wreg[4*k4+0] = v.x; wreg[4*k4+1] = v.y;
            wreg[4*k4+2] = v.z; wreg[4*k4+3] = v.w;
        }
    }
    float wih[8];
    #pragma unroll
    for (int k = 0; k < 8; ++k) wih[k] = w_ih[(size_t)u*8 + k];
    float bsum = b_ih[u] + b_hh[u];
    __syncthreads();
    for (int t = 0; t < T_TOT; ++t) {
        float a0 = bsum, a1 = 0.f, a2 = 0.f, a3 = 0.f;
        #pragma unroll
        for (int k = 0; k < 8; ++k) a0 += eall[t*8 + k]*wih[k];
        #pragma unroll
        for (int k = 0; k < 32; ++k) {
            a0 += h[4*k+0]*wreg[4*k+0];
            a1 += h[4*k+1]*wreg[4*k+1];
            a2 += h[4*k+2]*wreg[4*k+2];
            a3 += h[4*k+3]*wreg[4*k+3];
        }
        g[u] = (a0 + a1) + (a2 + a3);
        __syncthreads();
        if (u < 128) {
            float ig = 1.f/(1.f + __expf(-g[u]));
            float fg = 1.f/(1.f + __expf(-g[128+u]));
            float gg = tanhf(g[256+u]);
            float og = 1.f/(1.f + __expf(-g[384+u]));
            float cn = fg*cst[u] + ig*gg;
            cst[u] = cn;
            h[u] = og*tanhf(cn);
        }
        __syncthreads();
    }
    if (u < 64) {
        float p0 = h[u]*w_fc[u]       + h[u+64]*w_fc[64+u];
        float p1 = h[u]*w_fc[128+u]   + h[u+64]*w_fc[192+u];
        #pragma unroll
        for (int off = 32; off >= 1; off >>= 1) {
            p0 += __shfl_xor(p0, off, 64);
            p1 += __shfl_xor(p1, off, 64);
        }
        if (u == 0) {
            out[b*2 + 0] = p0 + b_fc[0];
            out[b*2 + 1] = p1 + b_fc[1];
        }
    }
}

extern "C" void kernel_launch(void* const* d_in, const int* in_sizes, int n_in,
                              void* d_out, int out_size, void* d_ws, size_t ws_size,
                              hipStream_t stream) {
    const float* x_seq = (const float*)d_in[0];
    const int*   edge  = (const int*)d_in[1];   // row0 = src
    const float* W1 = (const float*)d_in[3];
    const float* as1 = (const float*)d_in[4];
    const float* ad1 = (const float*)d_in[5];
    const float* b1  = (const float*)d_in[6];
    const float* W2 = (const float*)d_in[7];
    const float* as2 = (const float*)d_in[8];
    const float* ad2 = (const float*)d_in[9];
    const float* b2  = (const float*)d_in[10];
    const float* W3 = (const float*)d_in[11];
    const float* as3 = (const float*)d_in[12];
    const float* ad3 = (const float*)d_in[13];
    const float* b3  = (const float*)d_in[14];
    const float* W4 = (const float*)d_in[15];
    const float* as4 = (const float*)d_in[16];
    const float* ad4 = (const float*)d_in[17];
    const float* b4  = (const float*)d_in[18];
    const float* w_ih = (const float*)d_in[19];
    const float* w_hh = (const float*)d_in[20];
    const float* b_ih = (const float*)d_in[21];
    const float* b_hh = (const float*)d_in[22];
    const float* w_fc = (const float*)d_in[23];
    const float* b_fc = (const float*)d_in[24];

    char* w = (char*)d_ws;
    auto alloc = [&](size_t bytes) {
        char* p = w; w += (bytes + 255) & ~(size_t)255; return p;
    };
    float*   A1  = (float*)alloc(128);
    float*   emb = (float*)alloc((size_t)T_TOT*8*8*4);
    ushortT* W2T = (ushortT*)alloc((size_t)256*512*2);
    ushortT* W3T = (ushortT*)alloc((size_t)128*256*2);
    size_t used = (size_t)(w - (char*)d_ws);
    // per-row bytes: Q 1024 + P 512 + G3 512 + H3 256 + H4 32 + ES/ED 64 + ES4/ED4 8
    size_t perT = (size_t)NN*(1024 + 512 + 512 + 256 + 32 + 64 + 8 + 64);
    size_t rem = (ws_size > used + 4096) ? ws_size - used - 4096 : 0;
    int Tc = (int)(rem / perT);
    if (Tc > T_TOT) Tc = T_TOT;
    if (Tc < 1) Tc = 1;
    ushortT* Q   = (ushortT*)alloc((size_t)Tc*NN*1024);
    ushortT* P   = (ushortT*)alloc((size_t)Tc*NN*512);
    ushortT* G3  = (ushortT*)alloc((size_t)Tc*NN*512);
    ushortT* H3  = (ushortT*)alloc((size_t)Tc*NN*256);
    float*   H4  = (float*)alloc((size_t)Tc*NN*32);
    float*   ES  = (float*)alloc((size_t)Tc*NN*32);
    float*   ED  = (float*)alloc((size_t)Tc*NN*32);
    float*   ES4 = (float*)alloc((size_t)Tc*NN*4);
    float*   ED4 = (float*)alloc((size_t)Tc*NN*4);

    hipMemsetAsync(emb, 0, (size_t)T_TOT*8*8*4, stream);
    k_prep_l1<<<1, 64, 0, stream>>>(W1, as1, ad1, A1);
    k_prepW<<<(256*512 + 255)/256, 256, 0, stream>>>(W2, W2T, 512, 256);
    k_prepW<<<(128*256 + 255)/256, 256, 0, stream>>>(W3, W3T, 256, 128);

    for (int t0 = 0; t0 < T_TOT; t0 += Tc) {
        int tc = (Tc < T_TOT - t0) ? Tc : (T_TOT - t0);
        int R = tc*NN;
        int nrb = (R + 127)/128;
        const float* xoff = x_seq + (size_t)t0*NN*2;
        // Layer 1 (rank-2 + fused e-compute) -> bf16
        k_gat1<<<(R*8 + 31)/32, 256, 0, stream>>>(xoff, edge, A1, W1, b1, Q, R);
        // Layer 2: MFMA GEMM 512->256 (+es/ed), agg -> bf16
        k_gemm_mfma<32><<<dim3(nrb, 2), 512, 0, stream>>>(Q, W2T, as2, ad2, P, ES, ED, R, 512, 256);
        k_gat<8,32,4,true,true><<<(R*8 + 63)/64, 256, 0, stream>>>(P, edge, ES, ED, b2, nullptr, G3, R);
        // Layer 3: MFMA GEMM 256->128 (+es/ed), agg fused with layer-4 linear
        k_gemm_mfma<16><<<dim3(nrb, 1), 512, 0, stream>>>(G3, W3T, as3, ad3, H3, ES, ED, R, 256, 128);
        k_gat3_lin4<<<(R*8 + 127)/128, 256, 0, stream>>>(H3, edge, ES, ED, b3, W4, as4, ad4, H4, ES4, ED4, R);
        // Layer 4 aggregate fused with mean-pool -> emb (atomic)
        k_gat4_pool<<<(R + 127)/128, 256, 0, stream>>>(H4, edge, ES4, ED4, b4, emb, R, t0);
    }
    k_lstm<<<8, 512, 0, stream>>>(emb, w_ih, w_hh, b_ih, b_hh, w_fc, b_fc, (float*)d_out);
}